// Round 4
// baseline (1382.145 us; speedup 1.0000x reference)
//
#include <hip/hip_runtime.h>
#include <hip/hip_fp16.h>

// GCN_Embedding R12: layer-invariant node-granular sort + barrier/LDS/atomic-free
// accumulate kernels.
//  R11 residual: 7.7 cyc/edge in accums = gather (~3-5) + 3 DS ops + chunk
//  lockstep (5 barriers/chunk, 489-block grid, 43% occupancy). The dl-sort the
//  accum does per chunk is LAYER-INVARIANT -> hoist it into a one-time k_sort2
//  (bucket -> node-granular order + nodeoff{start,cnt}). Accums become
//  thread-per-node register streaming: no LDS, no barriers, no atomics,
//  4-deep unrolled gather for MLP, grid 1954x256 (full occupancy).
//  Needs +131MiB workspace (total 284MiB): runtime-dispatch with exact-R11
//  fallback if ws_size is insufficient.

constexpr int N_NODES = 500000;
constexpr int N_EDGES = 16000000;
constexpr int F = 5;
constexpr int NPB = 1024;                        // nodes per bucket (dst >> 10)
constexpr int K_BKT = (N_NODES + NPB - 1) / NPB; // 489
constexpr int CAP = 35008;                       // edges per bucket slot
constexpr int PART_BLOCKS = 1024;
constexpr int CHUNK = N_EDGES / PART_BLOCKS;     // 15625
constexpr int SUB = 3125;                        // k_part LDS-staged sub-chunk
constexpr int ACH = 4096;                        // fallback accum chunk
constexpr int ACC_BLOCKS = (N_NODES + 255) / 256; // 1954

// ---------- init fixed bucket tails ----------
__global__ void k_init(unsigned* __restrict__ gtail) {
    int b = blockIdx.x * blockDim.x + threadIdx.x;
    if (b < K_BKT) gtail[b] = (unsigned)(b * CAP);
}

// ---------- partition: LDS counting-sort staging (R9 version, unchanged) ----------
__global__ __launch_bounds__(512) void k_part(const int* __restrict__ src,
                                              const int* __restrict__ dst,
                                              const float* __restrict__ ew,
                                              unsigned* __restrict__ gtail,
                                              uint2* __restrict__ sorted) {
    __shared__ uint2 stage[SUB];
    __shared__ unsigned short sbkt[SUB];
    __shared__ unsigned hcnt[512];
    __shared__ unsigned scn[512];
    __shared__ unsigned gb2[512];
    const int t = threadIdx.x;
    const int base_e = blockIdx.x * CHUNK;

#pragma unroll 1
    for (int rnd = 0; rnd < CHUNK / SUB; ++rnd) {
        const int sub_lo = base_e + rnd * SUB;
        hcnt[t] = 0;
        __syncthreads();
        for (int e = sub_lo + t; e < sub_lo + SUB; e += 512)
            atomicAdd(&hcnt[(unsigned)dst[e] >> 10], 1u);
        __syncthreads();
        scn[t] = hcnt[t];
        __syncthreads();
        for (int d = 1; d < 512; d <<= 1) {
            unsigned add = (t >= d) ? scn[t - d] : 0u;
            __syncthreads();
            scn[t] += add;
            __syncthreads();
        }
        unsigned cnt = hcnt[t];
        scn[t] -= cnt;
        if (t < K_BKT && cnt)
            gb2[t] = atomicAdd(&gtail[t], cnt) - scn[t];
        __syncthreads();
        hcnt[t] = 0;
        __syncthreads();
        for (int e = sub_lo + t; e < sub_lo + SUB; e += 512) {
            unsigned d = (unsigned)__builtin_nontemporal_load(dst + e);
            unsigned bkt = d >> 10;
            unsigned p = scn[bkt] + atomicAdd(&hcnt[bkt], 1u);
            uint2 pay;
            pay.x = (unsigned)__builtin_nontemporal_load(src + e) | ((d & (NPB - 1u)) << 19);
            pay.y = __float_as_uint(__builtin_nontemporal_load(ew + e));
            stage[p] = pay;
            sbkt[p] = (unsigned short)bkt;
        }
        __syncthreads();
        for (int p = t; p < SUB; p += 512)
            sorted[gb2[sbkt[p]] + p] = stage[p];
        __syncthreads();
    }
}

// ---------- one-time node-granular sort within each bucket ----------
__global__ __launch_bounds__(1024) void k_sort2(const unsigned long long* __restrict__ in,
                                                const unsigned* __restrict__ gtail,
                                                uint2* __restrict__ nodeoff,
                                                unsigned long long* __restrict__ out) {
    __shared__ unsigned cnt[NPB];
    __shared__ unsigned excl[NPB];
    __shared__ unsigned wsum[16];
    const int t = threadIdx.x;
    const int wid = t >> 6, lane = t & 63;
    const unsigned b = blockIdx.x;
    const unsigned lo = b * CAP, hi = gtail[b];
    cnt[t] = 0;
    __syncthreads();
    // pass1: histogram (fire-and-forget atomics)
    for (unsigned e = lo + t; e < hi; e += 1024) {
        unsigned long long pe = __builtin_nontemporal_load(in + e);
        atomicAdd(&cnt[((unsigned)pe) >> 19], 1u);
    }
    __syncthreads();
    // scan: wave shfl inclusive + wave partials
    unsigned c = cnt[t];
    unsigned inc = c;
#pragma unroll
    for (int d = 1; d < 64; d <<= 1) {
        unsigned up = __shfl_up(inc, d);
        if (lane >= d) inc += up;
    }
    if (lane == 63) wsum[wid] = inc;
    __syncthreads();
    unsigned wbase = 0;
#pragma unroll
    for (int wv = 0; wv < 15; ++wv)
        if (wv < wid) wbase += wsum[wv];
    unsigned my_excl = wbase + inc - c;
    excl[t] = my_excl;
    int node = (int)(b * NPB) + t;
    if (node < N_NODES) nodeoff[node] = make_uint2(lo + my_excl, c);
    __syncthreads();
    cnt[t] = 0;
    __syncthreads();
    // pass2: scatter to node-sorted order (L2-local region, unroll 4 for MLP)
    unsigned e = lo + t;
    for (; e + 3072 < hi; e += 4096) {
        unsigned long long p0 = __builtin_nontemporal_load(in + e);
        unsigned long long p1 = __builtin_nontemporal_load(in + e + 1024);
        unsigned long long p2 = __builtin_nontemporal_load(in + e + 2048);
        unsigned long long p3 = __builtin_nontemporal_load(in + e + 3072);
        unsigned d0 = ((unsigned)p0) >> 19, d1 = ((unsigned)p1) >> 19;
        unsigned d2 = ((unsigned)p2) >> 19, d3 = ((unsigned)p3) >> 19;
        unsigned q0 = excl[d0] + atomicAdd(&cnt[d0], 1u);
        unsigned q1 = excl[d1] + atomicAdd(&cnt[d1], 1u);
        unsigned q2 = excl[d2] + atomicAdd(&cnt[d2], 1u);
        unsigned q3 = excl[d3] + atomicAdd(&cnt[d3], 1u);
        out[lo + q0] = p0;
        out[lo + q1] = p1;
        out[lo + q2] = p2;
        out[lo + q3] = p3;
    }
    for (; e < hi; e += 1024) {
        unsigned long long p0 = __builtin_nontemporal_load(in + e);
        unsigned d0 = ((unsigned)p0) >> 19;
        unsigned q0 = excl[d0] + atomicAdd(&cnt[d0], 1u);
        out[lo + q0] = p0;
    }
}

// ---------- x = h @ W^T, 5 x f16 packed per node in one uint4 ----------
__device__ __forceinline__ uint4 pack5(const float o[F]) {
    __half2 p01 = __floats2half2_rn(o[0], o[1]);
    __half2 p23 = __floats2half2_rn(o[2], o[3]);
    __half2 p4z = __floats2half2_rn(o[4], 0.f);
    uint4 pk;
    pk.x = *(const unsigned*)&p01;
    pk.y = *(const unsigned*)&p23;
    pk.z = *(const unsigned*)&p4z;
    pk.w = 0u;
    return pk;
}

__global__ void k_lin(const float* __restrict__ h, const float* __restrict__ W,
                      uint4* __restrict__ x) {
    int i = blockIdx.x * blockDim.x + threadIdx.x;
    if (i >= N_NODES) return;
    float hv[F], o[F];
#pragma unroll
    for (int k = 0; k < F; ++k) hv[k] = h[i * F + k];
#pragma unroll
    for (int f = 0; f < F; ++f) {
        float acc = 0.f;
#pragma unroll
        for (int k = 0; k < F; ++k) acc = fmaf(hv[k], W[f * F + k], acc);
        o[f] = acc;
    }
    x[i] = pack5(o);
}

// ---------- streaming per-node accumulate core (no LDS, no barriers) ----------
__device__ __forceinline__ void fma_edge(unsigned long long pe, const uint4& v,
                                         float acc[F]) {
    float w = __uint_as_float((unsigned)(pe >> 32));
    float2 f01 = __half22float2(*reinterpret_cast<const __half2*>(&v.x));
    float2 f23 = __half22float2(*reinterpret_cast<const __half2*>(&v.y));
    float2 f4z = __half22float2(*reinterpret_cast<const __half2*>(&v.z));
    acc[0] = fmaf(f01.x, w, acc[0]);
    acc[1] = fmaf(f01.y, w, acc[1]);
    acc[2] = fmaf(f23.x, w, acc[2]);
    acc[3] = fmaf(f23.y, w, acc[3]);
    acc[4] = fmaf(f4z.x, w, acc[4]);
}

__device__ __forceinline__ void node_accum(const unsigned long long* __restrict__ s2,
                                           uint2 oc, const uint4* __restrict__ x,
                                           float acc[F]) {
    unsigned i = 0;
    for (; i + 4 <= oc.y; i += 4) {
        unsigned long long e0 = s2[oc.x + i];
        unsigned long long e1 = s2[oc.x + i + 1];
        unsigned long long e2 = s2[oc.x + i + 2];
        unsigned long long e3 = s2[oc.x + i + 3];
        uint4 v0 = x[(unsigned)e0 & 0x7FFFFu];
        uint4 v1 = x[(unsigned)e1 & 0x7FFFFu];
        uint4 v2 = x[(unsigned)e2 & 0x7FFFFu];
        uint4 v3 = x[(unsigned)e3 & 0x7FFFFu];
        fma_edge(e0, v0, acc);
        fma_edge(e1, v1, acc);
        fma_edge(e2, v2, acc);
        fma_edge(e3, v3, acc);
    }
    for (; i < oc.y; ++i) {
        unsigned long long e0 = s2[oc.x + i];
        uint4 v0 = x[(unsigned)e0 & 0x7FFFFu];
        fma_edge(e0, v0, acc);
    }
}

// ---------- two-level accum + finish + next lin ----------
__global__ __launch_bounds__(256) void k_gacc2(const unsigned long long* __restrict__ s2,
                                               const uint2* __restrict__ nodeoff,
                                               const uint4* __restrict__ x,
                                               const float* __restrict__ bias,
                                               const float* __restrict__ Wn,
                                               uint4* __restrict__ xn) {
    int node = blockIdx.x * 256 + threadIdx.x;
    if (node >= N_NODES) return;
    uint2 oc = nodeoff[node];
    float acc[F] = {0.f, 0.f, 0.f, 0.f, 0.f};
    node_accum(s2, oc, x, acc);
    float inv = 1.0f / fmaxf((float)oc.y, 1.0f);
    float hv[F], o[F];
#pragma unroll
    for (int f = 0; f < F; ++f) hv[f] = fmaxf(fmaf(acc[f], inv, bias[f]), 0.f);
#pragma unroll
    for (int f = 0; f < F; ++f) {
        float s = 0.f;
#pragma unroll
        for (int kk = 0; kk < F; ++kk) s = fmaf(hv[kk], Wn[f * F + kk], s);
        o[f] = s;
    }
    xn[node] = pack5(o);
}

__global__ __launch_bounds__(256) void k_gfinal2(const unsigned long long* __restrict__ s2,
                                                 const uint2* __restrict__ nodeoff,
                                                 const uint4* __restrict__ x,
                                                 const float* __restrict__ b3,
                                                 const float* __restrict__ fcW1, const float* __restrict__ fcb1,
                                                 const float* __restrict__ fcW2, const float* __restrict__ fcb2,
                                                 const float* __restrict__ fcW3, const float* __restrict__ fcb3,
                                                 float* __restrict__ out) {
    int node = blockIdx.x * 256 + threadIdx.x;
    if (node >= N_NODES) return;
    uint2 oc = nodeoff[node];
    float acc[F] = {0.f, 0.f, 0.f, 0.f, 0.f};
    node_accum(s2, oc, x, acc);
    float inv = 1.0f / fmaxf((float)oc.y, 1.0f);
    float h3[F], t1[F], t2[F];
#pragma unroll
    for (int f = 0; f < F; ++f) h3[f] = fmaxf(fmaf(acc[f], inv, b3[f]), 0.f);
#pragma unroll
    for (int f = 0; f < F; ++f) {
        float s = fcb1[f];
#pragma unroll
        for (int kk = 0; kk < F; ++kk) s = fmaf(h3[kk], fcW1[f * F + kk], s);
        t1[f] = fmaxf(s, 0.f);
    }
#pragma unroll
    for (int f = 0; f < F; ++f) {
        float s = fcb2[f];
#pragma unroll
        for (int kk = 0; kk < F; ++kk) s = fmaf(t1[kk], fcW2[f * F + kk], s);
        t2[f] = fmaxf(s, 0.f);
    }
#pragma unroll
    for (int f = 0; f < F; ++f) {
        float s = fcb3[f];
#pragma unroll
        for (int kk = 0; kk < F; ++kk) s = fmaf(t2[kk], fcW3[f * F + kk], s);
        out[node * F + f] = s;
    }
}

// ================= R11 fallback accum (used if workspace too small) =================
__device__ __forceinline__ void accum_bucket(const unsigned long long* __restrict__ sorted,
                                             unsigned lo, unsigned hi,
                                             const uint4* __restrict__ x,
                                             unsigned long long* __restrict__ stage,
                                             unsigned* __restrict__ cnt,
                                             unsigned* __restrict__ excl,
                                             unsigned* __restrict__ wsum,
                                             float acc[F], float& deg) {
    const int t = threadIdx.x;
    const int wid = t >> 6, lane = t & 63;
    for (unsigned cb = lo; cb < hi; cb += ACH) {
        const unsigned n = min((unsigned)ACH, hi - cb);
        cnt[t] = 0;
        __syncthreads();
        unsigned long long pe[4];
        unsigned dl[4], rk[4];
#pragma unroll
        for (int i = 0; i < 4; ++i) {
            unsigned idx = (unsigned)t + i * 1024u;
            if (idx < n) {
                pe[i] = __builtin_nontemporal_load(sorted + cb + idx);
                dl[i] = ((unsigned)pe[i]) >> 19;
                rk[i] = atomicAdd(&cnt[dl[i]], 1u);
            }
        }
        __syncthreads();
        unsigned c = cnt[t];
        unsigned inc = c;
#pragma unroll
        for (int d = 1; d < 64; d <<= 1) {
            unsigned up = __shfl_up(inc, d);
            if (lane >= d) inc += up;
        }
        if (lane == 63) wsum[wid] = inc;
        __syncthreads();
        unsigned wbase = 0;
#pragma unroll
        for (int wv = 0; wv < 15; ++wv)
            if (wv < wid) wbase += wsum[wv];
        unsigned my_excl = wbase + inc - c;
        excl[t] = my_excl;
        __syncthreads();
#pragma unroll
        for (int i = 0; i < 4; ++i) {
            unsigned idx = (unsigned)t + i * 1024u;
            if (idx < n) stage[excl[dl[i]] + rk[i]] = pe[i];
        }
        __syncthreads();
        deg += (float)c;
        for (unsigned i = 0; i < c; ++i) {
            unsigned long long e = stage[my_excl + i];
            unsigned px = (unsigned)e;
            float w = __uint_as_float((unsigned)(e >> 32));
            uint4 v = x[px & 0x7FFFFu];
            float2 f01 = __half22float2(*reinterpret_cast<const __half2*>(&v.x));
            float2 f23 = __half22float2(*reinterpret_cast<const __half2*>(&v.y));
            float2 f4z = __half22float2(*reinterpret_cast<const __half2*>(&v.z));
            acc[0] = fmaf(f01.x, w, acc[0]);
            acc[1] = fmaf(f01.y, w, acc[1]);
            acc[2] = fmaf(f23.x, w, acc[2]);
            acc[3] = fmaf(f23.y, w, acc[3]);
            acc[4] = fmaf(f4z.x, w, acc[4]);
        }
        __syncthreads();
    }
}

__global__ __launch_bounds__(1024) void k_gacc(const unsigned long long* __restrict__ sorted,
                                               const unsigned* __restrict__ gtail,
                                               const uint4* __restrict__ x,
                                               const float* __restrict__ bias,
                                               const float* __restrict__ Wn,
                                               uint4* __restrict__ xn) {
    __shared__ unsigned long long stage[ACH];
    __shared__ unsigned cnt[NPB];
    __shared__ unsigned excl[NPB];
    __shared__ unsigned wsum[16];
    float acc[F] = {0.f, 0.f, 0.f, 0.f, 0.f};
    float deg = 0.f;
    const unsigned b = blockIdx.x;
    accum_bucket(sorted, b * CAP, gtail[b], x, stage, cnt, excl, wsum, acc, deg);
    int node = b * NPB + threadIdx.x;
    if (node < N_NODES) {
        float inv = 1.0f / fmaxf(deg, 1.0f);
        float hv[F], o[F];
#pragma unroll
        for (int f = 0; f < F; ++f) hv[f] = fmaxf(fmaf(acc[f], inv, bias[f]), 0.f);
#pragma unroll
        for (int f = 0; f < F; ++f) {
            float s = 0.f;
#pragma unroll
            for (int kk = 0; kk < F; ++kk) s = fmaf(hv[kk], Wn[f * F + kk], s);
            o[f] = s;
        }
        xn[node] = pack5(o);
    }
}

__global__ __launch_bounds__(1024) void k_gfinal(const unsigned long long* __restrict__ sorted,
                                                 const unsigned* __restrict__ gtail,
                                                 const uint4* __restrict__ x,
                                                 const float* __restrict__ b3,
                                                 const float* __restrict__ fcW1, const float* __restrict__ fcb1,
                                                 const float* __restrict__ fcW2, const float* __restrict__ fcb2,
                                                 const float* __restrict__ fcW3, const float* __restrict__ fcb3,
                                                 float* __restrict__ out) {
    __shared__ unsigned long long stage[ACH];
    __shared__ unsigned cnt[NPB];
    __shared__ unsigned excl[NPB];
    __shared__ unsigned wsum[16];
    float acc[F] = {0.f, 0.f, 0.f, 0.f, 0.f};
    float deg = 0.f;
    const unsigned b = blockIdx.x;
    accum_bucket(sorted, b * CAP, gtail[b], x, stage, cnt, excl, wsum, acc, deg);
    int node = b * NPB + threadIdx.x;
    if (node < N_NODES) {
        float inv = 1.0f / fmaxf(deg, 1.0f);
        float h3[F], t1[F], t2[F];
#pragma unroll
        for (int f = 0; f < F; ++f) h3[f] = fmaxf(fmaf(acc[f], inv, b3[f]), 0.f);
#pragma unroll
        for (int f = 0; f < F; ++f) {
            float s = fcb1[f];
#pragma unroll
            for (int kk = 0; kk < F; ++kk) s = fmaf(h3[kk], fcW1[f * F + kk], s);
            t1[f] = fmaxf(s, 0.f);
        }
#pragma unroll
        for (int f = 0; f < F; ++f) {
            float s = fcb2[f];
#pragma unroll
            for (int kk = 0; kk < F; ++kk) s = fmaf(t1[kk], fcW2[f * F + kk], s);
            t2[f] = fmaxf(s, 0.f);
        }
#pragma unroll
        for (int f = 0; f < F; ++f) {
            float s = fcb3[f];
#pragma unroll
            for (int kk = 0; kk < F; ++kk) s = fmaf(t2[kk], fcW3[f * F + kk], s);
            out[node * F + f] = s;
        }
    }
}

extern "C" void kernel_launch(void* const* d_in, const int* in_sizes, int n_in,
                              void* d_out, int out_size, void* d_ws, size_t ws_size,
                              hipStream_t stream) {
    const float* h    = (const float*)d_in[0];
    const int*   ei   = (const int*)d_in[1];
    const float* ew   = (const float*)d_in[2];
    const float* W1   = (const float*)d_in[3];
    const float* b1   = (const float*)d_in[4];
    const float* W2   = (const float*)d_in[5];
    const float* b2   = (const float*)d_in[6];
    const float* W3   = (const float*)d_in[7];
    const float* b3   = (const float*)d_in[8];
    const float* fcW1 = (const float*)d_in[9];
    const float* fcb1 = (const float*)d_in[10];
    const float* fcW2 = (const float*)d_in[11];
    const float* fcb2 = (const float*)d_in[12];
    const float* fcW3 = (const float*)d_in[13];
    const float* fcb3 = (const float*)d_in[14];
    float* out = (float*)d_out;

    const int* srcp = ei;
    const int* dstp = ei + N_EDGES;

    char* ws = (char*)d_ws;
    const size_t MiB = 1024 * 1024;
    const size_t SORT_BYTES = (size_t)K_BKT * CAP * 8; // 136,951,296
    unsigned* gtail   = (unsigned*)(ws + 0);            // 2 KB
    uint4*    xA      = (uint4*)(ws + 1 * MiB);         // 8 MB
    uint4*    xB      = (uint4*)(ws + 10 * MiB);        // 8 MB
    uint2*    nodeoff = (uint2*)(ws + 18 * MiB);        // 4 MB
    uint2*    sorted  = (uint2*)(ws + 22 * MiB);        // 130.6 MiB
    unsigned long long* sorted2 =
        (unsigned long long*)(ws + 153 * MiB);          // 130.6 MiB
    const unsigned long long* sorted64 = (const unsigned long long*)sorted;
    const size_t NEED = 153 * MiB + SORT_BYTES;         // ~283.6 MiB

    dim3 gn((N_NODES + 255) / 256);

    // --- fixed-capacity bucket partition (once, reused by all 3 layers) ---
    k_init<<<1, 512, 0, stream>>>(gtail);
    k_part<<<PART_BLOCKS, 512, 0, stream>>>(srcp, dstp, ew, gtail, sorted);
    k_lin<<<gn, 256, 0, stream>>>(h, W1, xA);

    if (ws_size >= NEED) {
        // --- one-time node-granular sort, then barrier/LDS-free accums ---
        k_sort2<<<K_BKT, 1024, 0, stream>>>(sorted64, gtail, nodeoff, sorted2);
        k_gacc2<<<ACC_BLOCKS, 256, 0, stream>>>(sorted2, nodeoff, xA, b1, W2, xB);
        k_gacc2<<<ACC_BLOCKS, 256, 0, stream>>>(sorted2, nodeoff, xB, b2, W3, xA);
        k_gfinal2<<<ACC_BLOCKS, 256, 0, stream>>>(sorted2, nodeoff, xA, b3,
                                                  fcW1, fcb1, fcW2, fcb2, fcW3, fcb3, out);
    } else {
        // --- R11 fallback path ---
        k_gacc<<<K_BKT, 1024, 0, stream>>>(sorted64, gtail, xA, b1, W2, xB);
        k_gacc<<<K_BKT, 1024, 0, stream>>>(sorted64, gtail, xB, b2, W3, xA);
        k_gfinal<<<K_BKT, 1024, 0, stream>>>(sorted64, gtail, xA, b3,
                                             fcW1, fcb1, fcW2, fcb2, fcW3, fcb3, out);
    }
}

// Round 5
// 1131.378 us; speedup vs baseline: 1.2216x; 1.2216x over previous
//
#include <hip/hip_runtime.h>
#include <hip/hip_fp16.h>

// GCN_Embedding R13: coalesced segmented-scan accumulate over (quarter,node)-
// sorted edges.
//  R12 lesson: per-thread segment streaming amplified edge FETCH 4.5x (998MB).
//  Edge stream must be consumed wave-coalesced exactly once (128MB).
//  k_sort2 sorts each bucket by key=(src>>17)<<10|dl (4096 keys) + emits deg.
//  Accum: lane-coalesced edge read -> x[src] gather -> 64-lane segmented
//  inclusive scan on the (monotone-within-window) key -> segment tails do
//  5x ds_add_f32 into LDS accf (~0.7 lane-atomics/edge). No hot-loop barriers.
//  Quarter-major order sweeps x in 2MB slices -> L2-resident gather (retests
//  R10's phasing hypothesis, now in a BW-bound regime where it can show).

constexpr int N_NODES = 500000;
constexpr int N_EDGES = 16000000;
constexpr int F = 5;
constexpr int NPB = 1024;                        // nodes per bucket (dst >> 10)
constexpr int K_BKT = (N_NODES + NPB - 1) / NPB; // 489
constexpr int CAP = 35008;                       // edges per bucket slot
constexpr int PART_BLOCKS = 1024;
constexpr int CHUNK = N_EDGES / PART_BLOCKS;     // 15625
constexpr int SUB = 3125;                        // k_part LDS-staged sub-chunk
constexpr int ACH = 4096;                        // fallback accum chunk
constexpr int NKEY = 4096;                       // (quarter,dl) sort keys

// ---------- init fixed bucket tails ----------
__global__ void k_init(unsigned* __restrict__ gtail) {
    int b = blockIdx.x * blockDim.x + threadIdx.x;
    if (b < K_BKT) gtail[b] = (unsigned)(b * CAP);
}

// ---------- partition: LDS counting-sort staging (R9 version, unchanged) ----------
__global__ __launch_bounds__(512) void k_part(const int* __restrict__ src,
                                              const int* __restrict__ dst,
                                              const float* __restrict__ ew,
                                              unsigned* __restrict__ gtail,
                                              uint2* __restrict__ sorted) {
    __shared__ uint2 stage[SUB];
    __shared__ unsigned short sbkt[SUB];
    __shared__ unsigned hcnt[512];
    __shared__ unsigned scn[512];
    __shared__ unsigned gb2[512];
    const int t = threadIdx.x;
    const int base_e = blockIdx.x * CHUNK;

#pragma unroll 1
    for (int rnd = 0; rnd < CHUNK / SUB; ++rnd) {
        const int sub_lo = base_e + rnd * SUB;
        hcnt[t] = 0;
        __syncthreads();
        for (int e = sub_lo + t; e < sub_lo + SUB; e += 512)
            atomicAdd(&hcnt[(unsigned)dst[e] >> 10], 1u);
        __syncthreads();
        scn[t] = hcnt[t];
        __syncthreads();
        for (int d = 1; d < 512; d <<= 1) {
            unsigned add = (t >= d) ? scn[t - d] : 0u;
            __syncthreads();
            scn[t] += add;
            __syncthreads();
        }
        unsigned cnt = hcnt[t];
        scn[t] -= cnt;
        if (t < K_BKT && cnt)
            gb2[t] = atomicAdd(&gtail[t], cnt) - scn[t];
        __syncthreads();
        hcnt[t] = 0;
        __syncthreads();
        for (int e = sub_lo + t; e < sub_lo + SUB; e += 512) {
            unsigned d = (unsigned)__builtin_nontemporal_load(dst + e);
            unsigned bkt = d >> 10;
            unsigned p = scn[bkt] + atomicAdd(&hcnt[bkt], 1u);
            uint2 pay;
            pay.x = (unsigned)__builtin_nontemporal_load(src + e) | ((d & (NPB - 1u)) << 19);
            pay.y = __float_as_uint(__builtin_nontemporal_load(ew + e));
            stage[p] = pay;
            sbkt[p] = (unsigned short)bkt;
        }
        __syncthreads();
        for (int p = t; p < SUB; p += 512)
            sorted[gb2[sbkt[p]] + p] = stage[p];
        __syncthreads();
    }
}

// ---------- one-time (quarter,node)-granular sort + per-node degree ----------
__global__ __launch_bounds__(1024) void k_sort2(const unsigned long long* __restrict__ in,
                                                const unsigned* __restrict__ gtail,
                                                float* __restrict__ deg,
                                                unsigned long long* __restrict__ out) {
    __shared__ unsigned hist[NKEY];   // 16 KB
    __shared__ unsigned excl[NKEY];   // 16 KB
    __shared__ unsigned wsum[16];
    const int t = threadIdx.x;
    const int wid = t >> 6, lane = t & 63;
    const unsigned b = blockIdx.x;
    const unsigned lo = b * CAP, hi = gtail[b];
    hist[t] = 0; hist[t + 1024] = 0; hist[t + 2048] = 0; hist[t + 3072] = 0;
    __syncthreads();
    // pass1: histogram over 4096 (quarter,dl) keys
    for (unsigned e = lo + t; e < hi; e += 1024) {
        unsigned long long pe = __builtin_nontemporal_load(in + e);
        unsigned px = (unsigned)pe;
        unsigned key = (((px & 0x7FFFFu) >> 17) << 10) | ((px >> 19) & 1023u);
        atomicAdd(&hist[key], 1u);
    }
    __syncthreads();
    // per-node degree (layer-invariant): sum over quarters
    deg[b * NPB + t] = (float)(hist[t] + hist[t + 1024] + hist[t + 2048] + hist[t + 3072]);
    // scan of 4096: 4-seq per thread + wave shfl scan + wave partials
    unsigned h0 = hist[4 * t], h1 = hist[4 * t + 1];
    unsigned h2 = hist[4 * t + 2], h3 = hist[4 * t + 3];
    unsigned ts = h0 + h1 + h2 + h3;
    unsigned inc = ts;
#pragma unroll
    for (int d = 1; d < 64; d <<= 1) {
        unsigned up = __shfl_up(inc, d);
        if (lane >= d) inc += up;
    }
    if (lane == 63) wsum[wid] = inc;
    __syncthreads();
    unsigned wbase = 0;
#pragma unroll
    for (int wv = 0; wv < 15; ++wv)
        if (wv < wid) wbase += wsum[wv];
    unsigned eb = wbase + inc - ts;
    excl[4 * t] = eb;
    excl[4 * t + 1] = eb + h0;
    excl[4 * t + 2] = eb + h0 + h1;
    excl[4 * t + 3] = eb + h0 + h1 + h2;
    __syncthreads();
    // pass2: scatter to (quarter,node)-sorted order (atomic returns position)
    unsigned e = lo + t;
    for (; e + 3072 < hi; e += 4096) {
        unsigned long long p0 = __builtin_nontemporal_load(in + e);
        unsigned long long p1 = __builtin_nontemporal_load(in + e + 1024);
        unsigned long long p2 = __builtin_nontemporal_load(in + e + 2048);
        unsigned long long p3 = __builtin_nontemporal_load(in + e + 3072);
        unsigned x0 = (unsigned)p0, x1 = (unsigned)p1, x2 = (unsigned)p2, x3 = (unsigned)p3;
        unsigned k0 = (((x0 & 0x7FFFFu) >> 17) << 10) | ((x0 >> 19) & 1023u);
        unsigned k1 = (((x1 & 0x7FFFFu) >> 17) << 10) | ((x1 >> 19) & 1023u);
        unsigned k2 = (((x2 & 0x7FFFFu) >> 17) << 10) | ((x2 >> 19) & 1023u);
        unsigned k3 = (((x3 & 0x7FFFFu) >> 17) << 10) | ((x3 >> 19) & 1023u);
        unsigned q0 = atomicAdd(&excl[k0], 1u);
        unsigned q1 = atomicAdd(&excl[k1], 1u);
        unsigned q2 = atomicAdd(&excl[k2], 1u);
        unsigned q3 = atomicAdd(&excl[k3], 1u);
        out[lo + q0] = p0;
        out[lo + q1] = p1;
        out[lo + q2] = p2;
        out[lo + q3] = p3;
    }
    for (; e < hi; e += 1024) {
        unsigned long long p0 = __builtin_nontemporal_load(in + e);
        unsigned x0 = (unsigned)p0;
        unsigned k0 = (((x0 & 0x7FFFFu) >> 17) << 10) | ((x0 >> 19) & 1023u);
        unsigned q0 = atomicAdd(&excl[k0], 1u);
        out[lo + q0] = p0;
    }
}

// ---------- x = h @ W^T, 5 x f16 packed per node in one uint4 ----------
__device__ __forceinline__ uint4 pack5(const float o[F]) {
    __half2 p01 = __floats2half2_rn(o[0], o[1]);
    __half2 p23 = __floats2half2_rn(o[2], o[3]);
    __half2 p4z = __floats2half2_rn(o[4], 0.f);
    uint4 pk;
    pk.x = *(const unsigned*)&p01;
    pk.y = *(const unsigned*)&p23;
    pk.z = *(const unsigned*)&p4z;
    pk.w = 0u;
    return pk;
}

__global__ void k_lin(const float* __restrict__ h, const float* __restrict__ W,
                      uint4* __restrict__ x) {
    int i = blockIdx.x * blockDim.x + threadIdx.x;
    if (i >= N_NODES) return;
    float hv[F], o[F];
#pragma unroll
    for (int k = 0; k < F; ++k) hv[k] = h[i * F + k];
#pragma unroll
    for (int f = 0; f < F; ++f) {
        float acc = 0.f;
#pragma unroll
        for (int k = 0; k < F; ++k) acc = fmaf(hv[k], W[f * F + k], acc);
        o[f] = acc;
    }
    x[i] = pack5(o);
}

// ---------- segmented-scan edge commit ----------
// Keys are monotone within each 64-consecutive-edge window (sort key order),
// so equality-merge segmented inclusive scan is exact. Tails write partial
// segment sums via ds_add_f32; partials across windows compose via atomics.
__device__ __forceinline__ void scan_commit(unsigned long long pe, uint4 v, bool valid,
                                            int lane, float* __restrict__ accf) {
    unsigned px = (unsigned)pe;
    float w = valid ? __uint_as_float((unsigned)(pe >> 32)) : 0.f;
    unsigned key = valid ? ((((px & 0x7FFFFu) >> 17) << 10) | ((px >> 19) & 1023u))
                         : 0xFFFFu;
    float2 f01 = __half22float2(*reinterpret_cast<const __half2*>(&v.x));
    float2 f23 = __half22float2(*reinterpret_cast<const __half2*>(&v.y));
    float2 f4z = __half22float2(*reinterpret_cast<const __half2*>(&v.z));
    float m0 = f01.x * w, m1 = f01.y * w, m2 = f23.x * w, m3 = f23.y * w, m4 = f4z.x * w;
#pragma unroll
    for (int d = 1; d < 64; d <<= 1) {
        unsigned ku = __shfl_up(key, d);
        float u0 = __shfl_up(m0, d);
        float u1 = __shfl_up(m1, d);
        float u2 = __shfl_up(m2, d);
        float u3 = __shfl_up(m3, d);
        float u4 = __shfl_up(m4, d);
        if (lane >= d && ku == key) { m0 += u0; m1 += u1; m2 += u2; m3 += u3; m4 += u4; }
    }
    unsigned kd = __shfl_down(key, 1);
    if (valid && (lane == 63 || kd != key)) {
        float* a = accf + (key & 1023u) * 5;
        unsafeAtomicAdd(a + 0, m0);
        unsafeAtomicAdd(a + 1, m1);
        unsafeAtomicAdd(a + 2, m2);
        unsafeAtomicAdd(a + 3, m3);
        unsafeAtomicAdd(a + 4, m4);
    }
}

// bucket-wide accumulate into LDS f32 accf[1024][5], coalesced + barrier-free
__device__ __forceinline__ void accum_scan(const unsigned long long* __restrict__ s2,
                                           unsigned lo, unsigned hi,
                                           const uint4* __restrict__ x,
                                           float* __restrict__ accf) {
    const int t = threadIdx.x, lane = t & 63;
    const unsigned n = hi - lo;
    const unsigned niter = (n + 1023u) >> 10;
    unsigned it = 0;
    for (; it + 2 <= niter; it += 2) {
        unsigned i0 = it * 1024u + (unsigned)t;
        unsigned i1 = i0 + 1024u;
        bool v0 = i0 < n, v1 = i1 < n;
        unsigned long long p0 = v0 ? __builtin_nontemporal_load(s2 + lo + i0) : 0ull;
        unsigned long long p1 = v1 ? __builtin_nontemporal_load(s2 + lo + i1) : 0ull;
        uint4 g0 = x[(unsigned)p0 & 0x7FFFFu];
        uint4 g1 = x[(unsigned)p1 & 0x7FFFFu];
        scan_commit(p0, g0, v0, lane, accf);
        scan_commit(p1, g1, v1, lane, accf);
    }
    for (; it < niter; ++it) {
        unsigned i0 = it * 1024u + (unsigned)t;
        bool v0 = i0 < n;
        unsigned long long p0 = v0 ? __builtin_nontemporal_load(s2 + lo + i0) : 0ull;
        uint4 g0 = x[(unsigned)p0 & 0x7FFFFu];
        scan_commit(p0, g0, v0, lane, accf);
    }
}

// ---------- accumulate + finish + next lin ----------
__global__ __launch_bounds__(1024) void k_gacc3(const unsigned long long* __restrict__ s2,
                                                const unsigned* __restrict__ gtail,
                                                const float* __restrict__ deg,
                                                const uint4* __restrict__ x,
                                                const float* __restrict__ bias,
                                                const float* __restrict__ Wn,
                                                uint4* __restrict__ xn) {
    __shared__ float accf[NPB * 5]; // 20 KB
    const int t = threadIdx.x;
    for (int i = t; i < NPB * 5; i += 1024) accf[i] = 0.f;
    __syncthreads();
    const unsigned b = blockIdx.x;
    accum_scan(s2, b * CAP, gtail[b], x, accf);
    __syncthreads();
    int node = b * NPB + t;
    if (node < N_NODES) {
        float inv = 1.0f / fmaxf(deg[node], 1.0f);
        float hv[F], o[F];
#pragma unroll
        for (int f = 0; f < F; ++f) hv[f] = fmaxf(fmaf(accf[t * 5 + f], inv, bias[f]), 0.f);
#pragma unroll
        for (int f = 0; f < F; ++f) {
            float s = 0.f;
#pragma unroll
            for (int kk = 0; kk < F; ++kk) s = fmaf(hv[kk], Wn[f * F + kk], s);
            o[f] = s;
        }
        xn[node] = pack5(o);
    }
}

__global__ __launch_bounds__(1024) void k_gfinal3(const unsigned long long* __restrict__ s2,
                                                  const unsigned* __restrict__ gtail,
                                                  const float* __restrict__ deg,
                                                  const uint4* __restrict__ x,
                                                  const float* __restrict__ b3,
                                                  const float* __restrict__ fcW1, const float* __restrict__ fcb1,
                                                  const float* __restrict__ fcW2, const float* __restrict__ fcb2,
                                                  const float* __restrict__ fcW3, const float* __restrict__ fcb3,
                                                  float* __restrict__ out) {
    __shared__ float accf[NPB * 5];
    const int t = threadIdx.x;
    for (int i = t; i < NPB * 5; i += 1024) accf[i] = 0.f;
    __syncthreads();
    const unsigned b = blockIdx.x;
    accum_scan(s2, b * CAP, gtail[b], x, accf);
    __syncthreads();
    int node = b * NPB + t;
    if (node < N_NODES) {
        float inv = 1.0f / fmaxf(deg[node], 1.0f);
        float h3[F], t1[F], t2[F];
#pragma unroll
        for (int f = 0; f < F; ++f) h3[f] = fmaxf(fmaf(accf[t * 5 + f], inv, b3[f]), 0.f);
#pragma unroll
        for (int f = 0; f < F; ++f) {
            float s = fcb1[f];
#pragma unroll
            for (int kk = 0; kk < F; ++kk) s = fmaf(h3[kk], fcW1[f * F + kk], s);
            t1[f] = fmaxf(s, 0.f);
        }
#pragma unroll
        for (int f = 0; f < F; ++f) {
            float s = fcb2[f];
#pragma unroll
            for (int kk = 0; kk < F; ++kk) s = fmaf(t1[kk], fcW2[f * F + kk], s);
            t2[f] = fmaxf(s, 0.f);
        }
#pragma unroll
        for (int f = 0; f < F; ++f) {
            float s = fcb3[f];
#pragma unroll
            for (int kk = 0; kk < F; ++kk) s = fmaf(t2[kk], fcW3[f * F + kk], s);
            out[node * F + f] = s;
        }
    }
}

// ================= R11 fallback accum (used if workspace too small) =================
__device__ __forceinline__ void accum_bucket(const unsigned long long* __restrict__ sorted,
                                             unsigned lo, unsigned hi,
                                             const uint4* __restrict__ x,
                                             unsigned long long* __restrict__ stage,
                                             unsigned* __restrict__ cnt,
                                             unsigned* __restrict__ excl,
                                             unsigned* __restrict__ wsum,
                                             float acc[F], float& deg) {
    const int t = threadIdx.x;
    const int wid = t >> 6, lane = t & 63;
    for (unsigned cb = lo; cb < hi; cb += ACH) {
        const unsigned n = min((unsigned)ACH, hi - cb);
        cnt[t] = 0;
        __syncthreads();
        unsigned long long pe[4];
        unsigned dl[4], rk[4];
#pragma unroll
        for (int i = 0; i < 4; ++i) {
            unsigned idx = (unsigned)t + i * 1024u;
            if (idx < n) {
                pe[i] = __builtin_nontemporal_load(sorted + cb + idx);
                dl[i] = ((unsigned)pe[i]) >> 19;
                rk[i] = atomicAdd(&cnt[dl[i]], 1u);
            }
        }
        __syncthreads();
        unsigned c = cnt[t];
        unsigned inc = c;
#pragma unroll
        for (int d = 1; d < 64; d <<= 1) {
            unsigned up = __shfl_up(inc, d);
            if (lane >= d) inc += up;
        }
        if (lane == 63) wsum[wid] = inc;
        __syncthreads();
        unsigned wbase = 0;
#pragma unroll
        for (int wv = 0; wv < 15; ++wv)
            if (wv < wid) wbase += wsum[wv];
        unsigned my_excl = wbase + inc - c;
        excl[t] = my_excl;
        __syncthreads();
#pragma unroll
        for (int i = 0; i < 4; ++i) {
            unsigned idx = (unsigned)t + i * 1024u;
            if (idx < n) stage[excl[dl[i]] + rk[i]] = pe[i];
        }
        __syncthreads();
        deg += (float)c;
        for (unsigned i = 0; i < c; ++i) {
            unsigned long long e = stage[my_excl + i];
            unsigned px = (unsigned)e;
            float w = __uint_as_float((unsigned)(e >> 32));
            uint4 v = x[px & 0x7FFFFu];
            float2 f01 = __half22float2(*reinterpret_cast<const __half2*>(&v.x));
            float2 f23 = __half22float2(*reinterpret_cast<const __half2*>(&v.y));
            float2 f4z = __half22float2(*reinterpret_cast<const __half2*>(&v.z));
            acc[0] = fmaf(f01.x, w, acc[0]);
            acc[1] = fmaf(f01.y, w, acc[1]);
            acc[2] = fmaf(f23.x, w, acc[2]);
            acc[3] = fmaf(f23.y, w, acc[3]);
            acc[4] = fmaf(f4z.x, w, acc[4]);
        }
        __syncthreads();
    }
}

__global__ __launch_bounds__(1024) void k_gacc(const unsigned long long* __restrict__ sorted,
                                               const unsigned* __restrict__ gtail,
                                               const uint4* __restrict__ x,
                                               const float* __restrict__ bias,
                                               const float* __restrict__ Wn,
                                               uint4* __restrict__ xn) {
    __shared__ unsigned long long stage[ACH];
    __shared__ unsigned cnt[NPB];
    __shared__ unsigned excl[NPB];
    __shared__ unsigned wsum[16];
    float acc[F] = {0.f, 0.f, 0.f, 0.f, 0.f};
    float deg = 0.f;
    const unsigned b = blockIdx.x;
    accum_bucket(sorted, b * CAP, gtail[b], x, stage, cnt, excl, wsum, acc, deg);
    int node = b * NPB + threadIdx.x;
    if (node < N_NODES) {
        float inv = 1.0f / fmaxf(deg, 1.0f);
        float hv[F], o[F];
#pragma unroll
        for (int f = 0; f < F; ++f) hv[f] = fmaxf(fmaf(acc[f], inv, bias[f]), 0.f);
#pragma unroll
        for (int f = 0; f < F; ++f) {
            float s = 0.f;
#pragma unroll
            for (int kk = 0; kk < F; ++kk) s = fmaf(hv[kk], Wn[f * F + kk], s);
            o[f] = s;
        }
        xn[node] = pack5(o);
    }
}

__global__ __launch_bounds__(1024) void k_gfinal(const unsigned long long* __restrict__ sorted,
                                                 const unsigned* __restrict__ gtail,
                                                 const uint4* __restrict__ x,
                                                 const float* __restrict__ b3,
                                                 const float* __restrict__ fcW1, const float* __restrict__ fcb1,
                                                 const float* __restrict__ fcW2, const float* __restrict__ fcb2,
                                                 const float* __restrict__ fcW3, const float* __restrict__ fcb3,
                                                 float* __restrict__ out) {
    __shared__ unsigned long long stage[ACH];
    __shared__ unsigned cnt[NPB];
    __shared__ unsigned excl[NPB];
    __shared__ unsigned wsum[16];
    float acc[F] = {0.f, 0.f, 0.f, 0.f, 0.f};
    float deg = 0.f;
    const unsigned b = blockIdx.x;
    accum_bucket(sorted, b * CAP, gtail[b], x, stage, cnt, excl, wsum, acc, deg);
    int node = b * NPB + threadIdx.x;
    if (node < N_NODES) {
        float inv = 1.0f / fmaxf(deg, 1.0f);
        float h3[F], t1[F], t2[F];
#pragma unroll
        for (int f = 0; f < F; ++f) h3[f] = fmaxf(fmaf(acc[f], inv, b3[f]), 0.f);
#pragma unroll
        for (int f = 0; f < F; ++f) {
            float s = fcb1[f];
#pragma unroll
            for (int kk = 0; kk < F; ++kk) s = fmaf(h3[kk], fcW1[f * F + kk], s);
            t1[f] = fmaxf(s, 0.f);
        }
#pragma unroll
        for (int f = 0; f < F; ++f) {
            float s = fcb2[f];
#pragma unroll
            for (int kk = 0; kk < F; ++kk) s = fmaf(t1[kk], fcW2[f * F + kk], s);
            t2[f] = fmaxf(s, 0.f);
        }
#pragma unroll
        for (int f = 0; f < F; ++f) {
            float s = fcb3[f];
#pragma unroll
            for (int kk = 0; kk < F; ++kk) s = fmaf(t2[kk], fcW3[f * F + kk], s);
            out[node * F + f] = s;
        }
    }
}

extern "C" void kernel_launch(void* const* d_in, const int* in_sizes, int n_in,
                              void* d_out, int out_size, void* d_ws, size_t ws_size,
                              hipStream_t stream) {
    const float* h    = (const float*)d_in[0];
    const int*   ei   = (const int*)d_in[1];
    const float* ew   = (const float*)d_in[2];
    const float* W1   = (const float*)d_in[3];
    const float* b1   = (const float*)d_in[4];
    const float* W2   = (const float*)d_in[5];
    const float* b2   = (const float*)d_in[6];
    const float* W3   = (const float*)d_in[7];
    const float* b3   = (const float*)d_in[8];
    const float* fcW1 = (const float*)d_in[9];
    const float* fcb1 = (const float*)d_in[10];
    const float* fcW2 = (const float*)d_in[11];
    const float* fcb2 = (const float*)d_in[12];
    const float* fcW3 = (const float*)d_in[13];
    const float* fcb3 = (const float*)d_in[14];
    float* out = (float*)d_out;

    const int* srcp = ei;
    const int* dstp = ei + N_EDGES;

    char* ws = (char*)d_ws;
    const size_t MiB = 1024 * 1024;
    const size_t SORT_BYTES = (size_t)K_BKT * CAP * 8; // 136,951,296
    unsigned* gtail   = (unsigned*)(ws + 0);            // 2 KB
    uint4*    xA      = (uint4*)(ws + 1 * MiB);         // 8 MB
    uint4*    xB      = (uint4*)(ws + 10 * MiB);        // 8 MB
    float*    deg     = (float*)(ws + 18 * MiB);        // 489*1024*4 ~ 1.91 MiB
    uint2*    sorted  = (uint2*)(ws + 22 * MiB);        // 130.6 MiB
    unsigned long long* sorted2 =
        (unsigned long long*)(ws + 153 * MiB);          // 130.6 MiB
    const unsigned long long* sorted64 = (const unsigned long long*)sorted;
    const size_t NEED = 153 * MiB + SORT_BYTES;         // ~283.6 MiB

    dim3 gn((N_NODES + 255) / 256);

    // --- fixed-capacity bucket partition (once, reused by all 3 layers) ---
    k_init<<<1, 512, 0, stream>>>(gtail);
    k_part<<<PART_BLOCKS, 512, 0, stream>>>(srcp, dstp, ew, gtail, sorted);
    k_lin<<<gn, 256, 0, stream>>>(h, W1, xA);

    if (ws_size >= NEED) {
        // --- one-time (quarter,node) sort + deg, then scan-based accums ---
        k_sort2<<<K_BKT, 1024, 0, stream>>>(sorted64, gtail, deg, sorted2);
        k_gacc3<<<K_BKT, 1024, 0, stream>>>(sorted2, gtail, deg, xA, b1, W2, xB);
        k_gacc3<<<K_BKT, 1024, 0, stream>>>(sorted2, gtail, deg, xB, b2, W3, xA);
        k_gfinal3<<<K_BKT, 1024, 0, stream>>>(sorted2, gtail, deg, xA, b3,
                                              fcW1, fcb1, fcW2, fcb2, fcW3, fcb3, out);
    } else {
        // --- R11 fallback path ---
        k_gacc<<<K_BKT, 1024, 0, stream>>>(sorted64, gtail, xA, b1, W2, xB);
        k_gacc<<<K_BKT, 1024, 0, stream>>>(sorted64, gtail, xB, b2, W3, xA);
        k_gfinal<<<K_BKT, 1024, 0, stream>>>(sorted64, gtail, xA, b3,
                                             fcW1, fcb1, fcW2, fcb2, fcW3, fcb3, out);
    }
}

// Round 6
// 895.903 us; speedup vs baseline: 1.5427x; 1.2628x over previous
//
#include <hip/hip_runtime.h>
#include <hip/hip_fp16.h>

// GCN_Embedding R14: consolidate to R11 (best measured, 934us) + two targeted
// fixes from counter arithmetic:
//  (1) k_part run-boundary partial-line writes (~200MB excess WRITE_SIZE =
//      2 lines x 1024blk x 5rnd x 489bkt): PART_BLOCKS 1000 / SUB 4000 ->
//      runs 6.4->8.2 edges, ~20% fewer boundary lines, LDS 45KB (3 blk/CU).
//  (2) accum P4 lane imbalance (owner work Poisson(4), wave time = max lane
//      ~ 2.8x mean): ACH 4096->6144 (lambda=6 -> 2.3x) with in-place excl
//      (hist array reused, 52KB total), + next-chunk edge loads issued before
//      the stage barrier so they complete under P4 (hides load latency).
//  R12/R13 lesson encoded: two-level sort loses (sort2 cost > 3x accum gain);
//  single-level bucket sort + in-accum chunk sort is the winning shape.

constexpr int N_NODES = 500000;
constexpr int N_EDGES = 16000000;
constexpr int F = 5;
constexpr int NPB = 1024;                        // nodes per bucket (dst >> 10)
constexpr int K_BKT = (N_NODES + NPB - 1) / NPB; // 489
constexpr int CAP = 35008;                       // edges per bucket slot
constexpr int PART_BLOCKS = 1000;
constexpr int CHUNK = N_EDGES / PART_BLOCKS;     // 16000
constexpr int SUB = 4000;                        // k_part LDS-staged sub-chunk (4 rounds)
constexpr int ACH = 6144;                        // accum chunk (48KB LDS stage, 6/thread)

// ---------- init fixed bucket tails ----------
__global__ void k_init(unsigned* __restrict__ gtail) {
    int b = blockIdx.x * blockDim.x + threadIdx.x;
    if (b < K_BKT) gtail[b] = (unsigned)(b * CAP);
}

// ---------- partition: LDS counting-sort staging ----------
__global__ __launch_bounds__(512) void k_part(const int* __restrict__ src,
                                              const int* __restrict__ dst,
                                              const float* __restrict__ ew,
                                              unsigned* __restrict__ gtail,
                                              uint2* __restrict__ sorted) {
    __shared__ uint2 stage[SUB];           // 32000 B staged payload
    __shared__ unsigned short sbkt[SUB];   // 8000 B bucket id per staged slot
    __shared__ unsigned hcnt[512];         // per-round bucket counts / rank ctrs
    __shared__ unsigned scn[512];          // scan workspace -> exclusive offsets
    __shared__ unsigned gb2[512];          // global_base - local_off per bucket
    const int t = threadIdx.x;
    const int base_e = blockIdx.x * CHUNK;

#pragma unroll 1
    for (int rnd = 0; rnd < CHUNK / SUB; ++rnd) {
        const int sub_lo = base_e + rnd * SUB;
        hcnt[t] = 0;
        __syncthreads();
        for (int e = sub_lo + t; e < sub_lo + SUB; e += 512)
            atomicAdd(&hcnt[(unsigned)dst[e] >> 10], 1u);
        __syncthreads();
        scn[t] = hcnt[t];
        __syncthreads();
        for (int d = 1; d < 512; d <<= 1) {
            unsigned add = (t >= d) ? scn[t - d] : 0u;
            __syncthreads();
            scn[t] += add;
            __syncthreads();
        }
        unsigned cnt = hcnt[t];
        scn[t] -= cnt; // exclusive scan (own-element, no race)
        if (t < K_BKT && cnt)
            gb2[t] = atomicAdd(&gtail[t], cnt) - scn[t];
        __syncthreads();
        hcnt[t] = 0; // reuse as rank counters
        __syncthreads();
        for (int e = sub_lo + t; e < sub_lo + SUB; e += 512) {
            unsigned d = (unsigned)__builtin_nontemporal_load(dst + e);
            unsigned bkt = d >> 10;
            unsigned p = scn[bkt] + atomicAdd(&hcnt[bkt], 1u);
            uint2 pay;
            pay.x = (unsigned)__builtin_nontemporal_load(src + e) | ((d & (NPB - 1u)) << 19);
            pay.y = __float_as_uint(__builtin_nontemporal_load(ew + e));
            stage[p] = pay;
            sbkt[p] = (unsigned short)bkt;
        }
        __syncthreads();
        for (int p = t; p < SUB; p += 512)
            sorted[gb2[sbkt[p]] + p] = stage[p];
        __syncthreads();
    }
}

// ---------- x = h @ W^T, 5 x f16 packed per node in one uint4 ----------
__device__ __forceinline__ uint4 pack5(const float o[F]) {
    __half2 p01 = __floats2half2_rn(o[0], o[1]);
    __half2 p23 = __floats2half2_rn(o[2], o[3]);
    __half2 p4z = __floats2half2_rn(o[4], 0.f);
    uint4 pk;
    pk.x = *(const unsigned*)&p01;
    pk.y = *(const unsigned*)&p23;
    pk.z = *(const unsigned*)&p4z;
    pk.w = 0u;
    return pk;
}

__global__ void k_lin(const float* __restrict__ h, const float* __restrict__ W,
                      uint4* __restrict__ x) {
    int i = blockIdx.x * blockDim.x + threadIdx.x;
    if (i >= N_NODES) return;
    float hv[F], o[F];
#pragma unroll
    for (int k = 0; k < F; ++k) hv[k] = h[i * F + k];
#pragma unroll
    for (int f = 0; f < F; ++f) {
        float acc = 0.f;
#pragma unroll
        for (int k = 0; k < F; ++k) acc = fmaf(hv[k], W[f * F + k], acc);
        o[f] = acc;
    }
    x[i] = pack5(o);
}

__device__ __forceinline__ void fma_edge(unsigned long long pe, const uint4& v,
                                         float acc[F]) {
    float w = __uint_as_float((unsigned)(pe >> 32));
    float2 f01 = __half22float2(*reinterpret_cast<const __half2*>(&v.x));
    float2 f23 = __half22float2(*reinterpret_cast<const __half2*>(&v.y));
    float2 f4z = __half22float2(*reinterpret_cast<const __half2*>(&v.z));
    acc[0] = fmaf(f01.x, w, acc[0]);
    acc[1] = fmaf(f01.y, w, acc[1]);
    acc[2] = fmaf(f23.x, w, acc[2]);
    acc[3] = fmaf(f23.y, w, acc[3]);
    acc[4] = fmaf(f4z.x, w, acc[4]);
}

// ---------- chunked ownership accumulate (pipelined, in-place excl) ----------
// Per ACH=6144 chunk: 1 LDS hist atomic/edge (old value = rank), shfl scan,
// excl written in-place over the hist array, plain-write scatter into LDS
// stage, owner-thread f32 register accumulation. Next chunk's 6 edge loads are
// issued BEFORE the stage-ready barrier so HBM latency hides under P4.
__device__ __forceinline__ void accum_bucket(const unsigned long long* __restrict__ sorted,
                                             unsigned lo, unsigned hi,
                                             const uint4* __restrict__ x,
                                             unsigned long long* __restrict__ stage,
                                             unsigned* __restrict__ cntx,
                                             unsigned* __restrict__ wsum,
                                             float acc[F], float& deg) {
    const int t = threadIdx.x;
    const int wid = t >> 6, lane = t & 63;
    // prologue: load chunk 0 edges to regs
    unsigned long long pe[6];
    bool val[6];
    {
        unsigned n0 = hi - lo;
        if (n0 > (unsigned)ACH) n0 = ACH;
#pragma unroll
        for (int i = 0; i < 6; ++i) {
            unsigned idx = (unsigned)t + i * 1024u;
            val[i] = idx < n0;
            pe[i] = val[i] ? __builtin_nontemporal_load(sorted + lo + idx) : 0ull;
        }
    }
    for (unsigned cb = lo; cb < hi; cb += ACH) {
        cntx[t] = 0;
        __syncthreads();                                   // (A)
        // P1: hist atomic returns rank
        unsigned dl[6], rk[6];
#pragma unroll
        for (int i = 0; i < 6; ++i) {
            dl[i] = ((unsigned)pe[i]) >> 19;
            if (val[i]) rk[i] = atomicAdd(&cntx[dl[i]], 1u);
        }
        __syncthreads();                                   // (B)
        // scan: wave shfl inclusive + wave partials
        unsigned c = cntx[t];
        unsigned inc = c;
#pragma unroll
        for (int d = 1; d < 64; d <<= 1) {
            unsigned up = __shfl_up(inc, d);
            if (lane >= d) inc += up;
        }
        if (lane == 63) wsum[wid] = inc;
        __syncthreads();                                   // (C)
        unsigned wbase = 0;
#pragma unroll
        for (int wv = 0; wv < 15; ++wv)
            if (wv < wid) wbase += wsum[wv];
        unsigned my_excl = wbase + inc - c;
        cntx[t] = my_excl;          // in-place excl (own element, post-(C) safe)
        __syncthreads();                                   // (D)
        // P3: scatter payloads into dl-sorted LDS stage (plain writes)
#pragma unroll
        for (int i = 0; i < 6; ++i)
            if (val[i]) stage[cntx[dl[i]] + rk[i]] = pe[i];
        // issue NEXT chunk's loads now -> they complete under P4
        {
            unsigned cb2 = cb + ACH;
            unsigned n2 = (cb2 < hi) ? (hi - cb2) : 0u;
            if (n2 > (unsigned)ACH) n2 = ACH;
#pragma unroll
            for (int i = 0; i < 6; ++i) {
                unsigned idx = (unsigned)t + i * 1024u;
                val[i] = idx < n2;
                pe[i] = val[i] ? __builtin_nontemporal_load(sorted + cb2 + idx) : 0ull;
            }
        }
        __syncthreads();                                   // (E) stage ready
        // P4: owner accumulates its contiguous segment in f32 registers
        deg += (float)c;
        unsigned i = 0;
        for (; i + 4 <= c; i += 4) {
            unsigned long long e0 = stage[my_excl + i];
            unsigned long long e1 = stage[my_excl + i + 1];
            unsigned long long e2 = stage[my_excl + i + 2];
            unsigned long long e3 = stage[my_excl + i + 3];
            uint4 v0 = x[(unsigned)e0 & 0x7FFFFu];
            uint4 v1 = x[(unsigned)e1 & 0x7FFFFu];
            uint4 v2 = x[(unsigned)e2 & 0x7FFFFu];
            uint4 v3 = x[(unsigned)e3 & 0x7FFFFu];
            fma_edge(e0, v0, acc);
            fma_edge(e1, v1, acc);
            fma_edge(e2, v2, acc);
            fma_edge(e3, v3, acc);
        }
        for (; i < c; ++i) {
            unsigned long long e0 = stage[my_excl + i];
            uint4 v0 = x[(unsigned)e0 & 0x7FFFFu];
            fma_edge(e0, v0, acc);
        }
        __syncthreads();                                   // (F) stage/cntx reuse
    }
}

// ---------- per-bucket accumulate + finish + next lin (1024 thr) ----------
__global__ __launch_bounds__(1024) void k_gacc(const unsigned long long* __restrict__ sorted,
                                               const unsigned* __restrict__ gtail,
                                               const uint4* __restrict__ x,
                                               const float* __restrict__ bias,
                                               const float* __restrict__ Wn,
                                               uint4* __restrict__ xn) {
    __shared__ unsigned long long stage[ACH]; // 48 KB
    __shared__ unsigned cntx[NPB];            // 4 KB (hist -> excl in-place)
    __shared__ unsigned wsum[16];
    float acc[F] = {0.f, 0.f, 0.f, 0.f, 0.f};
    float deg = 0.f;
    const unsigned b = blockIdx.x;
    accum_bucket(sorted, b * CAP, gtail[b], x, stage, cntx, wsum, acc, deg);
    int node = b * NPB + threadIdx.x;
    if (node < N_NODES) {
        float inv = 1.0f / fmaxf(deg, 1.0f);
        float hv[F], o[F];
#pragma unroll
        for (int f = 0; f < F; ++f) hv[f] = fmaxf(fmaf(acc[f], inv, bias[f]), 0.f);
#pragma unroll
        for (int f = 0; f < F; ++f) {
            float s = 0.f;
#pragma unroll
            for (int kk = 0; kk < F; ++kk) s = fmaf(hv[kk], Wn[f * F + kk], s);
            o[f] = s;
        }
        xn[node] = pack5(o);
    }
}

// ---------- last layer: accumulate + finish + full FC chain (f32 out) ----------
__global__ __launch_bounds__(1024) void k_gfinal(const unsigned long long* __restrict__ sorted,
                                                 const unsigned* __restrict__ gtail,
                                                 const uint4* __restrict__ x,
                                                 const float* __restrict__ b3,
                                                 const float* __restrict__ fcW1, const float* __restrict__ fcb1,
                                                 const float* __restrict__ fcW2, const float* __restrict__ fcb2,
                                                 const float* __restrict__ fcW3, const float* __restrict__ fcb3,
                                                 float* __restrict__ out) {
    __shared__ unsigned long long stage[ACH];
    __shared__ unsigned cntx[NPB];
    __shared__ unsigned wsum[16];
    float acc[F] = {0.f, 0.f, 0.f, 0.f, 0.f};
    float deg = 0.f;
    const unsigned b = blockIdx.x;
    accum_bucket(sorted, b * CAP, gtail[b], x, stage, cntx, wsum, acc, deg);
    int node = b * NPB + threadIdx.x;
    if (node < N_NODES) {
        float inv = 1.0f / fmaxf(deg, 1.0f);
        float h3[F], t1[F], t2[F];
#pragma unroll
        for (int f = 0; f < F; ++f) h3[f] = fmaxf(fmaf(acc[f], inv, b3[f]), 0.f);
#pragma unroll
        for (int f = 0; f < F; ++f) {
            float s = fcb1[f];
#pragma unroll
            for (int kk = 0; kk < F; ++kk) s = fmaf(h3[kk], fcW1[f * F + kk], s);
            t1[f] = fmaxf(s, 0.f);
        }
#pragma unroll
        for (int f = 0; f < F; ++f) {
            float s = fcb2[f];
#pragma unroll
            for (int kk = 0; kk < F; ++kk) s = fmaf(t1[kk], fcW2[f * F + kk], s);
            t2[f] = fmaxf(s, 0.f);
        }
#pragma unroll
        for (int f = 0; f < F; ++f) {
            float s = fcb3[f];
#pragma unroll
            for (int kk = 0; kk < F; ++kk) s = fmaf(t2[kk], fcW3[f * F + kk], s);
            out[node * F + f] = s;
        }
    }
}

extern "C" void kernel_launch(void* const* d_in, const int* in_sizes, int n_in,
                              void* d_out, int out_size, void* d_ws, size_t ws_size,
                              hipStream_t stream) {
    const float* h    = (const float*)d_in[0];
    const int*   ei   = (const int*)d_in[1];
    const float* ew   = (const float*)d_in[2];
    const float* W1   = (const float*)d_in[3];
    const float* b1   = (const float*)d_in[4];
    const float* W2   = (const float*)d_in[5];
    const float* b2   = (const float*)d_in[6];
    const float* W3   = (const float*)d_in[7];
    const float* b3   = (const float*)d_in[8];
    const float* fcW1 = (const float*)d_in[9];
    const float* fcb1 = (const float*)d_in[10];
    const float* fcW2 = (const float*)d_in[11];
    const float* fcb2 = (const float*)d_in[12];
    const float* fcW3 = (const float*)d_in[13];
    const float* fcb3 = (const float*)d_in[14];
    float* out = (float*)d_out;

    const int* srcp = ei;
    const int* dstp = ei + N_EDGES;

    char* ws = (char*)d_ws;
    const size_t MiB = 1024 * 1024;
    unsigned* gtail   = (unsigned*)(ws + 0);           // 2 KB
    uint4*    xA      = (uint4*)(ws + 1 * MiB);        // 8 MB
    uint4*    xB      = (uint4*)(ws + 10 * MiB);       // 8 MB
    uint2*    sorted  = (uint2*)(ws + 19 * MiB);       // 489*35008*8 = 131 MiB
    const unsigned long long* sorted64 = (const unsigned long long*)sorted;

    dim3 gn((N_NODES + 255) / 256);

    // --- fixed-capacity bucket partition (once, reused by all 3 layers) ---
    k_init<<<1, 512, 0, stream>>>(gtail);
    k_part<<<PART_BLOCKS, 512, 0, stream>>>(srcp, dstp, ew, gtail, sorted);

    // --- layer pipeline ---
    k_lin<<<gn, 256, 0, stream>>>(h, W1, xA);
    k_gacc<<<K_BKT, 1024, 0, stream>>>(sorted64, gtail, xA, b1, W2, xB);
    k_gacc<<<K_BKT, 1024, 0, stream>>>(sorted64, gtail, xB, b2, W3, xA);
    k_gfinal<<<K_BKT, 1024, 0, stream>>>(sorted64, gtail, xA, b3,
                                         fcW1, fcb1, fcW2, fcb2, fcW3, fcb3, out);
}